// Round 1
// baseline (343.739 us; speedup 1.0000x reference)
//
#include <hip/hip_runtime.h>
#include <math.h>

// Problem constants (fixed by setup_inputs: B=8, H=W=64, C=256, sr=8)
static constexpr int Bb  = 8;
static constexpr int Nn  = 4096;   // H*W
static constexpr int Cc  = 256;
static constexpr int Wd  = 64;     // image H == W
static constexpr int HDm = 32;     // head dim
static constexpr int N1c = 256;    // 16x16 after 4x down
static constexpr int N2c = 64;     // 8x8 after 8x down

// =============== GEMM: Out[m,n] = sum_k A[m,k]*Wt[n,k] (+ bias[n]) ===============
// A: [M,256] row-major, Wt: [256,256] row-major (weights, used transposed).
// BM=BN=64, BK=16, 256 threads, 4x4 microtile per thread.
template<bool BIAS>
__global__ __launch_bounds__(256)
void gemm_atw(const float* __restrict__ A, const float* __restrict__ Wt,
              const float* __restrict__ bias, float* __restrict__ Out, int M) {
  constexpr int K = Cc;
  __shared__ float As[16][68];   // [k][m], pad 68 keeps float4 alignment + 2-way banks
  __shared__ float Bs[16][68];   // [k][n]
  const int tid = threadIdx.x;
  const int m0 = blockIdx.x * 64;
  const int n0 = blockIdx.y * 64;
  const int lr = tid >> 2;       // 0..63 tile row for loads
  const int lq = tid & 3;        // float4 index along K
  const int tx = tid & 15, ty = tid >> 4;
  float acc[4][4] = {};
  for (int k0 = 0; k0 < K; k0 += 16) {
    float4 av = *(const float4*)(A  + (size_t)(m0 + lr) * K + k0 + lq * 4);
    float4 bv = *(const float4*)(Wt + (size_t)(n0 + lr) * K + k0 + lq * 4);
    __syncthreads();   // previous iteration finished reading LDS
    As[lq*4+0][lr] = av.x; As[lq*4+1][lr] = av.y;
    As[lq*4+2][lr] = av.z; As[lq*4+3][lr] = av.w;
    Bs[lq*4+0][lr] = bv.x; Bs[lq*4+1][lr] = bv.y;
    Bs[lq*4+2][lr] = bv.z; Bs[lq*4+3][lr] = bv.w;
    __syncthreads();
#pragma unroll
    for (int k = 0; k < 16; ++k) {
      float4 a = *(const float4*)&As[k][ty * 4];
      float4 b = *(const float4*)&Bs[k][tx * 4];
      acc[0][0] = fmaf(a.x, b.x, acc[0][0]); acc[0][1] = fmaf(a.x, b.y, acc[0][1]);
      acc[0][2] = fmaf(a.x, b.z, acc[0][2]); acc[0][3] = fmaf(a.x, b.w, acc[0][3]);
      acc[1][0] = fmaf(a.y, b.x, acc[1][0]); acc[1][1] = fmaf(a.y, b.y, acc[1][1]);
      acc[1][2] = fmaf(a.y, b.z, acc[1][2]); acc[1][3] = fmaf(a.y, b.w, acc[1][3]);
      acc[2][0] = fmaf(a.z, b.x, acc[2][0]); acc[2][1] = fmaf(a.z, b.y, acc[2][1]);
      acc[2][2] = fmaf(a.z, b.z, acc[2][2]); acc[2][3] = fmaf(a.z, b.w, acc[2][3]);
      acc[3][0] = fmaf(a.w, b.x, acc[3][0]); acc[3][1] = fmaf(a.w, b.y, acc[3][1]);
      acc[3][2] = fmaf(a.w, b.z, acc[3][2]); acc[3][3] = fmaf(a.w, b.w, acc[3][3]);
    }
  }
  const int nc = n0 + tx * 4;
  float4 bb = make_float4(0.f, 0.f, 0.f, 0.f);
  if (BIAS) bb = *(const float4*)(bias + nc);
#pragma unroll
  for (int i = 0; i < 4; ++i) {
    float4 o = make_float4(acc[i][0] + bb.x, acc[i][1] + bb.y,
                           acc[i][2] + bb.z, acc[i][3] + bb.w);
    *(float4*)(Out + (size_t)(m0 + ty * 4 + i) * Cc + nc) = o;
  }
}

// =============== fused: depthwise KSxKS stride-KS conv + bias + LN + exact GELU =======
template<int KS, int HO>
__global__ __launch_bounds__(256)
void down_ln_gelu(const float* __restrict__ x, const float* __restrict__ w,
                  const float* __restrict__ cb, const float* __restrict__ g,
                  const float* __restrict__ lb, float* __restrict__ xo) {
  const int b = blockIdx.y;
  const int n1 = blockIdx.x;            // output pixel: i*HO + j
  const int i = n1 / HO, j = n1 % HO;
  const int c = threadIdx.x;            // channel
  const float* wc = w + c * KS * KS;
  const float* xb = x + ((size_t)b * Nn) * Cc + c;
  float acc = cb[c];
#pragma unroll
  for (int dy = 0; dy < KS; ++dy) {
#pragma unroll
    for (int dx = 0; dx < KS; ++dx) {
      int n = (i * KS + dy) * Wd + (j * KS + dx);
      acc = fmaf(wc[dy * KS + dx], xb[(size_t)n * Cc], acc);
    }
  }
  // LayerNorm over C=256 (one value per thread)
  float s = acc, s2 = acc * acc;
#pragma unroll
  for (int off = 32; off; off >>= 1) {
    s  += __shfl_down(s, off);
    s2 += __shfl_down(s2, off);
  }
  __shared__ float rs[4], rq[4];
  if ((c & 63) == 0) { rs[c >> 6] = s; rq[c >> 6] = s2; }
  __syncthreads();
  float sum = rs[0] + rs[1] + rs[2] + rs[3];
  float sq  = rq[0] + rq[1] + rq[2] + rq[3];
  float mean = sum * (1.f / Cc);
  float var  = sq * (1.f / Cc) - mean * mean;
  float xn = (acc - mean) * rsqrtf(var + 1e-5f) * g[c] + lb[c];
  float gel = 0.5f * xn * (1.f + erff(xn * 0.70710678118654752440f));
  xo[((size_t)b * (HO * HO) + n1) * Cc + c] = gel;
}

// =============== v_new = v + dwconv3x3(v) + bias  (v = channels 128.. of kv) =========
template<int HS>
__global__ __launch_bounds__(128)
void vconv(const float* __restrict__ kv, const float* __restrict__ w,
           const float* __restrict__ bias, float* __restrict__ vo) {
  constexpr int NS = HS * HS;
  const int b = blockIdx.y;
  const int n1 = blockIdx.x;
  const int i = n1 / HS, j = n1 % HS;
  const int c = threadIdx.x;            // 0..127
  const float* vb = kv + ((size_t)b * NS) * Cc + 128 + c;
  const float* wc = w + c * 9;
  float acc = bias[c];
#pragma unroll
  for (int dy = 0; dy < 3; ++dy) {
    int ii = i + dy - 1;
    if (ii < 0 || ii >= HS) continue;
#pragma unroll
    for (int dx = 0; dx < 3; ++dx) {
      int jj = j + dx - 1;
      if (jj < 0 || jj >= HS) continue;
      acc = fmaf(wc[dy * 3 + dx], vb[(size_t)(ii * HS + jj) * Cc], acc);
    }
  }
  vo[((size_t)b * NS + n1) * 128 + c] = acc + vb[(size_t)n1 * Cc];
}

// =============== attention: softmax(Q K^T * scale) @ V_new, in-place q->o ============
// grid (chunk, h, b); 256 threads, 2 query rows/thread (512 rows per block).
// Reads q[b, r, cq..cq+31], writes output to the SAME slice (disjoint across blocks).
template<int NS>
__global__ __launch_bounds__(256)
void attn(float* __restrict__ qo, const float* __restrict__ kv,
          const float* __restrict__ vnew, const int branch) {
  constexpr float scale = 0.17677669529663688f;  // 32^-0.5
  __shared__ float Ks[64][32];
  __shared__ float Vs[64][32];
  const int t = threadIdx.x;
  const int h = blockIdx.y;
  const int b = blockIdx.z;
  const int cq = branch * 128 + h * HDm;
  const int ck = h * HDm;
  const int r0 = blockIdx.x * 512 + t;
  const int r1 = r0 + 256;

  float* qp0 = qo + ((size_t)b * Nn + r0) * Cc + cq;
  float* qp1 = qo + ((size_t)b * Nn + r1) * Cc + cq;
  float q0[32], q1[32];
#pragma unroll
  for (int d4 = 0; d4 < 8; ++d4) {
    float4 v0 = *(const float4*)(qp0 + d4 * 4);
    float4 v1 = *(const float4*)(qp1 + d4 * 4);
    q0[d4*4+0] = v0.x; q0[d4*4+1] = v0.y; q0[d4*4+2] = v0.z; q0[d4*4+3] = v0.w;
    q1[d4*4+0] = v1.x; q1[d4*4+1] = v1.y; q1[d4*4+2] = v1.z; q1[d4*4+3] = v1.w;
  }
  float acc0[32] = {}, acc1[32] = {};
  float m0 = -1e30f, m1 = -1e30f, l0 = 0.f, l1 = 0.f;

  for (int j0 = 0; j0 < NS; j0 += 64) {
    __syncthreads();
    {
      const int jj = t >> 3;     // 0..31
      const int d4 = t & 7;      // 0..7
      const float* kp = kv   + ((size_t)(b * NS + j0 + jj)) * Cc  + ck + d4 * 4;
      const float* vp = vnew + ((size_t)(b * NS + j0 + jj)) * 128 + ck + d4 * 4;
      *(float4*)&Ks[jj][d4*4]    = *(const float4*)kp;
      *(float4*)&Ks[jj+32][d4*4] = *(const float4*)(kp + 32 * Cc);
      *(float4*)&Vs[jj][d4*4]    = *(const float4*)vp;
      *(float4*)&Vs[jj+32][d4*4] = *(const float4*)(vp + 32 * 128);
    }
    __syncthreads();
#pragma unroll 2
    for (int jj = 0; jj < 64; ++jj) {
      float s0 = 0.f, s1 = 0.f;
#pragma unroll
      for (int d4 = 0; d4 < 8; ++d4) {
        float4 kk = *(const float4*)&Ks[jj][d4 * 4];
        s0 = fmaf(q0[d4*4+0], kk.x, s0); s0 = fmaf(q0[d4*4+1], kk.y, s0);
        s0 = fmaf(q0[d4*4+2], kk.z, s0); s0 = fmaf(q0[d4*4+3], kk.w, s0);
        s1 = fmaf(q1[d4*4+0], kk.x, s1); s1 = fmaf(q1[d4*4+1], kk.y, s1);
        s1 = fmaf(q1[d4*4+2], kk.z, s1); s1 = fmaf(q1[d4*4+3], kk.w, s1);
      }
      s0 *= scale; s1 *= scale;
      if (s0 > m0) {                      // lazy rescale (rare)
        float cr = __expf(m0 - s0); l0 *= cr;
#pragma unroll
        for (int d = 0; d < 32; ++d) acc0[d] *= cr;
        m0 = s0;
      }
      float p0 = __expf(s0 - m0); l0 += p0;
      if (s1 > m1) {
        float cr = __expf(m1 - s1); l1 *= cr;
#pragma unroll
        for (int d = 0; d < 32; ++d) acc1[d] *= cr;
        m1 = s1;
      }
      float p1 = __expf(s1 - m1); l1 += p1;
#pragma unroll
      for (int d4 = 0; d4 < 8; ++d4) {
        float4 vv = *(const float4*)&Vs[jj][d4 * 4];
        acc0[d4*4+0] = fmaf(p0, vv.x, acc0[d4*4+0]);
        acc0[d4*4+1] = fmaf(p0, vv.y, acc0[d4*4+1]);
        acc0[d4*4+2] = fmaf(p0, vv.z, acc0[d4*4+2]);
        acc0[d4*4+3] = fmaf(p0, vv.w, acc0[d4*4+3]);
        acc1[d4*4+0] = fmaf(p1, vv.x, acc1[d4*4+0]);
        acc1[d4*4+1] = fmaf(p1, vv.y, acc1[d4*4+1]);
        acc1[d4*4+2] = fmaf(p1, vv.z, acc1[d4*4+2]);
        acc1[d4*4+3] = fmaf(p1, vv.w, acc1[d4*4+3]);
      }
    }
  }
  const float i0 = 1.f / l0, i1 = 1.f / l1;
#pragma unroll
  for (int d4 = 0; d4 < 8; ++d4) {
    float4 o0 = make_float4(acc0[d4*4+0]*i0, acc0[d4*4+1]*i0,
                            acc0[d4*4+2]*i0, acc0[d4*4+3]*i0);
    float4 o1 = make_float4(acc1[d4*4+0]*i1, acc1[d4*4+1]*i1,
                            acc1[d4*4+2]*i1, acc1[d4*4+3]*i1);
    *(float4*)(qp0 + d4 * 4) = o0;
    *(float4*)(qp1 + d4 * 4) = o1;
  }
}

extern "C" void kernel_launch(void* const* d_in, const int* in_sizes, int n_in,
                              void* d_out, int out_size, void* d_ws, size_t ws_size,
                              hipStream_t stream) {
  const float* x      = (const float*)d_in[0];
  const float* q_w    = (const float*)d_in[1];
  const float* kv1_w  = (const float*)d_in[2];
  const float* kv2_w  = (const float*)d_in[3];
  const float* proj_w = (const float*)d_in[4];
  const float* proj_b = (const float*)d_in[5];
  const float* sr1_w  = (const float*)d_in[6];
  const float* sr1_b  = (const float*)d_in[7];
  const float* sr2_w  = (const float*)d_in[8];
  const float* sr2_b  = (const float*)d_in[9];
  const float* ln1_g  = (const float*)d_in[10];
  const float* ln1_b  = (const float*)d_in[11];
  const float* ln2_g  = (const float*)d_in[12];
  const float* ln2_b  = (const float*)d_in[13];
  const float* lc1_w  = (const float*)d_in[14];
  const float* lc1_b  = (const float*)d_in[15];
  const float* lc2_w  = (const float*)d_in[16];
  const float* lc2_b  = (const float*)d_in[17];
  float* out = (float*)d_out;
  float* ws  = (float*)d_ws;

  // workspace layout (floats); total ~10.03M floats = 40.1 MB
  float* q   = ws;                                   // [B,N,C]  (becomes o in-place)
  float* x1  = q   + (size_t)Bb * Nn  * Cc;          // [B,N1,C]
  float* kv1 = x1  + (size_t)Bb * N1c * Cc;          // [B,N1,C]
  float* vn1 = kv1 + (size_t)Bb * N1c * Cc;          // [B,N1,128]
  float* x2  = vn1 + (size_t)Bb * N1c * (Cc / 2);    // [B,N2,C]
  float* kv2 = x2  + (size_t)Bb * N2c * Cc;          // [B,N2,C]
  float* vn2 = kv2 + (size_t)Bb * N2c * Cc;          // [B,N2,128]

  // 1) q = x @ q_w^T
  gemm_atw<false><<<dim3(Bb * Nn / 64, 4), 256, 0, stream>>>(x, q_w, nullptr, q, Bb * Nn);
  // 2) spatial reductions + LN + GELU
  down_ln_gelu<4, 16><<<dim3(N1c, Bb), 256, 0, stream>>>(x, sr1_w, sr1_b, ln1_g, ln1_b, x1);
  down_ln_gelu<8, 8><<<dim3(N2c, Bb), 256, 0, stream>>>(x, sr2_w, sr2_b, ln2_g, ln2_b, x2);
  // 3) kv projections
  gemm_atw<false><<<dim3(Bb * N1c / 64, 4), 256, 0, stream>>>(x1, kv1_w, nullptr, kv1, Bb * N1c);
  gemm_atw<false><<<dim3(Bb * N2c / 64, 4), 256, 0, stream>>>(x2, kv2_w, nullptr, kv2, Bb * N2c);
  // 4) v + local depthwise conv
  vconv<16><<<dim3(N1c, Bb), 128, 0, stream>>>(kv1, lc1_w, lc1_b, vn1);
  vconv<8><<<dim3(N2c, Bb), 128, 0, stream>>>(kv2, lc2_w, lc2_b, vn2);
  // 5) attention (in-place on q buffer; channel slices disjoint per head/branch)
  attn<256><<<dim3(8, 4, Bb), 256, 0, stream>>>(q, kv1, vn1, 0);
  attn<64><<<dim3(8, 4, Bb), 256, 0, stream>>>(q, kv2, vn2, 1);
  // 6) projection + bias
  gemm_atw<true><<<dim3(Bb * Nn / 64, 4), 256, 0, stream>>>(q, proj_w, proj_b, out, Bb * Nn);
}

// Round 2
// 245.830 us; speedup vs baseline: 1.3983x; 1.3983x over previous
//
#include <hip/hip_runtime.h>
#include <math.h>

// Problem constants (fixed by setup_inputs: B=8, H=W=64, C=256, sr=8)
static constexpr int Bb  = 8;
static constexpr int Nn  = 4096;   // H*W
static constexpr int Cc  = 256;
static constexpr int Wd  = 64;     // image H == W
static constexpr int N1c = 256;    // 16x16 after 4x down
static constexpr int N2c = 64;     // 8x8 after 8x down

typedef __attribute__((ext_vector_type(8)))  short s16x8;   // 8 bf16 (4 VGPR)
typedef __attribute__((ext_vector_type(4)))  float f32x4v;  // MFMA acc

__device__ __forceinline__ unsigned short f2bf(float f) {
  unsigned u = __float_as_uint(f);
  unsigned r = (u + 0x7fffu + ((u >> 16) & 1u)) >> 16;   // RTN-even
  return (unsigned short)r;
}
__device__ __forceinline__ float bf2f(unsigned short h) {
  return __uint_as_float(((unsigned)h) << 16);
}

// ============ prepass: split 4 [256x256] fp32 weights into bf16 hi/lo ============
__global__ __launch_bounds__(256)
void cvt4(const float* __restrict__ w0, const float* __restrict__ w1,
          const float* __restrict__ w2, const float* __restrict__ w3,
          unsigned short* __restrict__ hi, unsigned short* __restrict__ lo) {
  const int wsel = blockIdx.y;
  const float* w = wsel == 0 ? w0 : wsel == 1 ? w1 : wsel == 2 ? w2 : w3;
  const int i = (blockIdx.x * 256 + threadIdx.x) * 4;
  float4 v = *(const float4*)(w + i);
  unsigned short h0 = f2bf(v.x), h1 = f2bf(v.y), h2 = f2bf(v.z), h3 = f2bf(v.w);
  ushort4 hh = make_ushort4(h0, h1, h2, h3);
  ushort4 ll = make_ushort4(f2bf(v.x - bf2f(h0)), f2bf(v.y - bf2f(h1)),
                            f2bf(v.z - bf2f(h2)), f2bf(v.w - bf2f(h3)));
  *(ushort4*)(hi + (size_t)wsel * 65536 + i) = hh;
  *(ushort4*)(lo + (size_t)wsel * 65536 + i) = ll;
}

// ============ GEMM: Out[m,n] = sum_k A[m,k]*W[n,k] (+bias), split-bf16 MFMA =======
// A fp32 [M,256] (split to hi/lo in-register during staging); W pre-split bf16.
// BM=64, BN=256 (full), BK=32, 256 thr = 4 waves; wave w owns cols w*64..w*64+63.
// MFMA 16x16x32_bf16 (verified layouts): A/B frag = 8 contiguous-k bf16 at
// row/col = lane&15, koff = (lane>>4)*8; C: col=lane&15, row=(lane>>4)*4+reg.
template<bool BIAS>
__global__ __launch_bounds__(256)
void gemm_mfma(const float* __restrict__ A, const unsigned short* __restrict__ Wh,
               const unsigned short* __restrict__ Wl, const float* __restrict__ bias,
               float* __restrict__ Out) {
  __shared__ unsigned short Ah[64][40], Al[64][40];     // 80 B rows: 16B-aligned, 2-way banks
  __shared__ unsigned short BhS[256][40], BlS[256][40];
  const int tid  = threadIdx.x;
  const int lane = tid & 63, wid = tid >> 6;
  const int m0 = blockIdx.x * 64;
  const int ar = tid >> 2;              // A stage row 0..63
  const int ak = (tid & 3) * 8;         // A stage k-offset

  f32x4v acc[4][4] = {};                // [mt][nt]

  const float*          Arow  = A  + (size_t)(m0 + ar) * 256 + ak;
  const unsigned short* WhRow = Wh + (size_t)tid * 256;
  const unsigned short* WlRow = Wl + (size_t)tid * 256;

  for (int k0 = 0; k0 < 256; k0 += 32) {
    // -------- global loads for this K-step (issued before barrier) --------
    float4 a0 = *(const float4*)(Arow + k0);
    float4 a1 = *(const float4*)(Arow + k0 + 4);
    uint4 wh0 = *(const uint4*)(WhRow + k0);
    uint4 wh1 = *(const uint4*)(WhRow + k0 + 8);
    uint4 wh2 = *(const uint4*)(WhRow + k0 + 16);
    uint4 wh3 = *(const uint4*)(WhRow + k0 + 24);
    uint4 wl0 = *(const uint4*)(WlRow + k0);
    uint4 wl1 = *(const uint4*)(WlRow + k0 + 8);
    uint4 wl2 = *(const uint4*)(WlRow + k0 + 16);
    uint4 wl3 = *(const uint4*)(WlRow + k0 + 24);
    __syncthreads();                    // prior iteration done reading LDS
    // -------- A: split fp32 -> bf16 hi/lo, pack, write --------
    float fv[8] = {a0.x, a0.y, a0.z, a0.w, a1.x, a1.y, a1.z, a1.w};
    unsigned h[8], l[8];
#pragma unroll
    for (int i = 0; i < 8; ++i) {
      h[i] = f2bf(fv[i]);
      l[i] = f2bf(fv[i] - bf2f((unsigned short)h[i]));
    }
    uint4 hp = make_uint4(h[0] | (h[1] << 16), h[2] | (h[3] << 16),
                          h[4] | (h[5] << 16), h[6] | (h[7] << 16));
    uint4 lp = make_uint4(l[0] | (l[1] << 16), l[2] | (l[3] << 16),
                          l[4] | (l[5] << 16), l[6] | (l[7] << 16));
    *(uint4*)&Ah[ar][ak] = hp;
    *(uint4*)&Al[ar][ak] = lp;
    // -------- W: direct bf16 copy (row = tid) --------
    *(uint4*)&BhS[tid][0]  = wh0; *(uint4*)&BhS[tid][8]  = wh1;
    *(uint4*)&BhS[tid][16] = wh2; *(uint4*)&BhS[tid][24] = wh3;
    *(uint4*)&BlS[tid][0]  = wl0; *(uint4*)&BlS[tid][8]  = wl1;
    *(uint4*)&BlS[tid][16] = wl2; *(uint4*)&BlS[tid][24] = wl3;
    __syncthreads();
    // -------- MFMA: 4mt x 4nt x 3 split terms --------
    const int koff = (lane >> 4) * 8;
    const int arow = lane & 15;
    s16x8 ah[4], al4[4];
#pragma unroll
    for (int mt = 0; mt < 4; ++mt) {
      ah[mt]  = *(const s16x8*)&Ah[mt * 16 + arow][koff];
      al4[mt] = *(const s16x8*)&Al[mt * 16 + arow][koff];
    }
#pragma unroll
    for (int nt = 0; nt < 4; ++nt) {
      const int col = wid * 64 + nt * 16 + (lane & 15);
      s16x8 bh = *(const s16x8*)&BhS[col][koff];
      s16x8 bl = *(const s16x8*)&BlS[col][koff];
#pragma unroll
      for (int mt = 0; mt < 4; ++mt) {
        acc[mt][nt] = __builtin_amdgcn_mfma_f32_16x16x32_bf16(ah[mt],  bh, acc[mt][nt], 0, 0, 0);
        acc[mt][nt] = __builtin_amdgcn_mfma_f32_16x16x32_bf16(ah[mt],  bl, acc[mt][nt], 0, 0, 0);
        acc[mt][nt] = __builtin_amdgcn_mfma_f32_16x16x32_bf16(al4[mt], bh, acc[mt][nt], 0, 0, 0);
      }
    }
  }
  // -------- epilogue: C col=lane&15, row=(lane>>4)*4+reg --------
#pragma unroll
  for (int nt = 0; nt < 4; ++nt) {
    const int col = wid * 64 + nt * 16 + (lane & 15);
    const float bv = BIAS ? bias[col] : 0.f;
#pragma unroll
    for (int mt = 0; mt < 4; ++mt) {
#pragma unroll
      for (int r = 0; r < 4; ++r) {
        const int row = m0 + mt * 16 + (lane >> 4) * 4 + r;
        Out[(size_t)row * 256 + col] = acc[mt][nt][r] + bv;
      }
    }
  }
}

// =============== fused: depthwise KSxKS stride-KS conv + bias + LN + exact GELU =======
template<int KS, int HO>
__global__ __launch_bounds__(256)
void down_ln_gelu(const float* __restrict__ x, const float* __restrict__ w,
                  const float* __restrict__ cb, const float* __restrict__ g,
                  const float* __restrict__ lb, float* __restrict__ xo) {
  const int b = blockIdx.y;
  const int n1 = blockIdx.x;
  const int i = n1 / HO, j = n1 % HO;
  const int c = threadIdx.x;
  const float* wc = w + c * KS * KS;
  const float* xb = x + ((size_t)b * Nn) * Cc + c;
  float acc = cb[c];
#pragma unroll
  for (int dy = 0; dy < KS; ++dy) {
#pragma unroll
    for (int dx = 0; dx < KS; ++dx) {
      int n = (i * KS + dy) * Wd + (j * KS + dx);
      acc = fmaf(wc[dy * KS + dx], xb[(size_t)n * Cc], acc);
    }
  }
  float s = acc, s2 = acc * acc;
#pragma unroll
  for (int off = 32; off; off >>= 1) {
    s  += __shfl_down(s, off);
    s2 += __shfl_down(s2, off);
  }
  __shared__ float rs[4], rq[4];
  if ((c & 63) == 0) { rs[c >> 6] = s; rq[c >> 6] = s2; }
  __syncthreads();
  float sum = rs[0] + rs[1] + rs[2] + rs[3];
  float sq  = rq[0] + rq[1] + rq[2] + rq[3];
  float mean = sum * (1.f / Cc);
  float var  = sq * (1.f / Cc) - mean * mean;
  float xn = (acc - mean) * rsqrtf(var + 1e-5f) * g[c] + lb[c];
  float gel = 0.5f * xn * (1.f + erff(xn * 0.70710678118654752440f));
  xo[((size_t)b * (HO * HO) + n1) * Cc + c] = gel;
}

// =============== v_new = v + dwconv3x3(v) + bias  (v = channels 128.. of kv) =========
template<int HS>
__global__ __launch_bounds__(128)
void vconv(const float* __restrict__ kv, const float* __restrict__ w,
           const float* __restrict__ bias, float* __restrict__ vo) {
  constexpr int NS = HS * HS;
  const int b = blockIdx.y;
  const int n1 = blockIdx.x;
  const int i = n1 / HS, j = n1 % HS;
  const int c = threadIdx.x;
  const float* vb = kv + ((size_t)b * NS) * Cc + 128 + c;
  const float* wc = w + c * 9;
  float acc = bias[c];
#pragma unroll
  for (int dy = 0; dy < 3; ++dy) {
    int ii = i + dy - 1;
    if (ii < 0 || ii >= HS) continue;
#pragma unroll
    for (int dx = 0; dx < 3; ++dx) {
      int jj = j + dx - 1;
      if (jj < 0 || jj >= HS) continue;
      acc = fmaf(wc[dy * 3 + dx], vb[(size_t)(ii * HS + jj) * Cc], acc);
    }
  }
  vo[((size_t)b * NS + n1) * 128 + c] = acc + vb[(size_t)n1 * Cc];
}

// =============== attention v2: whole K/V resident in LDS, no main-loop barriers ======
// grid (16, 4 heads, 8 b); 256 thr; 1 query row/thread. In-place q -> o (slices
// disjoint across blocks). NS=256: LDS 73.7 KB -> 2 blocks/CU, 8 waves/CU.
template<int NS>
__global__ __launch_bounds__(256)
void attn2(float* __restrict__ qo, const float* __restrict__ kv,
           const float* __restrict__ vnew, const int branch) {
  constexpr float scale = 0.17677669529663688f;  // 32^-0.5
  __shared__ float Ks[NS][36];
  __shared__ float Vs[NS][36];
  const int t = threadIdx.x;
  const int h = blockIdx.y, b = blockIdx.z;
  const int cq = branch * 128 + h * 32, ck = h * 32;
  if (t < NS) {
    const float* kp = kv   + ((size_t)(b * NS + t)) * Cc  + ck;
    const float* vp = vnew + ((size_t)(b * NS + t)) * 128 + ck;
#pragma unroll
    for (int d4 = 0; d4 < 8; ++d4) {
      *(float4*)&Ks[t][d4 * 4] = *(const float4*)(kp + d4 * 4);
      *(float4*)&Vs[t][d4 * 4] = *(const float4*)(vp + d4 * 4);
    }
  }
  const int r = blockIdx.x * 256 + t;
  float* qp = qo + ((size_t)b * Nn + r) * Cc + cq;
  float q[32], acc[32] = {};
#pragma unroll
  for (int d4 = 0; d4 < 8; ++d4) {
    float4 v = *(const float4*)(qp + d4 * 4);
    q[d4*4+0] = v.x; q[d4*4+1] = v.y; q[d4*4+2] = v.z; q[d4*4+3] = v.w;
  }
  float m = -1e30f, lsum = 0.f;
  __syncthreads();
  for (int j = 0; j < NS; ++j) {
    float s = 0.f;
#pragma unroll
    for (int d4 = 0; d4 < 8; ++d4) {
      float4 kk = *(const float4*)&Ks[j][d4 * 4];
      s = fmaf(q[d4*4+0], kk.x, s); s = fmaf(q[d4*4+1], kk.y, s);
      s = fmaf(q[d4*4+2], kk.z, s); s = fmaf(q[d4*4+3], kk.w, s);
    }
    s *= scale;
    if (s > m) {                        // lazy rescale (rare)
      float cr = __expf(m - s); lsum *= cr;
#pragma unroll
      for (int d = 0; d < 32; ++d) acc[d] *= cr;
      m = s;
    }
    float p = __expf(s - m); lsum += p;
#pragma unroll
    for (int d4 = 0; d4 < 8; ++d4) {
      float4 vv = *(const float4*)&Vs[j][d4 * 4];
      acc[d4*4+0] = fmaf(p, vv.x, acc[d4*4+0]);
      acc[d4*4+1] = fmaf(p, vv.y, acc[d4*4+1]);
      acc[d4*4+2] = fmaf(p, vv.z, acc[d4*4+2]);
      acc[d4*4+3] = fmaf(p, vv.w, acc[d4*4+3]);
    }
  }
  const float inv = 1.f / lsum;
#pragma unroll
  for (int d4 = 0; d4 < 8; ++d4) {
    float4 o = make_float4(acc[d4*4+0]*inv, acc[d4*4+1]*inv,
                           acc[d4*4+2]*inv, acc[d4*4+3]*inv);
    *(float4*)(qp + d4 * 4) = o;
  }
}

extern "C" void kernel_launch(void* const* d_in, const int* in_sizes, int n_in,
                              void* d_out, int out_size, void* d_ws, size_t ws_size,
                              hipStream_t stream) {
  const float* x      = (const float*)d_in[0];
  const float* q_w    = (const float*)d_in[1];
  const float* kv1_w  = (const float*)d_in[2];
  const float* kv2_w  = (const float*)d_in[3];
  const float* proj_w = (const float*)d_in[4];
  const float* proj_b = (const float*)d_in[5];
  const float* sr1_w  = (const float*)d_in[6];
  const float* sr1_b  = (const float*)d_in[7];
  const float* sr2_w  = (const float*)d_in[8];
  const float* sr2_b  = (const float*)d_in[9];
  const float* ln1_g  = (const float*)d_in[10];
  const float* ln1_b  = (const float*)d_in[11];
  const float* ln2_g  = (const float*)d_in[12];
  const float* ln2_b  = (const float*)d_in[13];
  const float* lc1_w  = (const float*)d_in[14];
  const float* lc1_b  = (const float*)d_in[15];
  const float* lc2_w  = (const float*)d_in[16];
  const float* lc2_b  = (const float*)d_in[17];
  float* out = (float*)d_out;
  float* ws  = (float*)d_ws;

  // workspace: 10.03M floats + 0.5M ushorts hi + 0.5M lo  (~41.1 MB)
  float* q   = ws;                                   // [B,N,C] (becomes o in-place)
  float* x1  = q   + (size_t)Bb * Nn  * Cc;
  float* kv1 = x1  + (size_t)Bb * N1c * Cc;
  float* vn1 = kv1 + (size_t)Bb * N1c * Cc;
  float* x2  = vn1 + (size_t)Bb * N1c * (Cc / 2);
  float* kv2 = x2  + (size_t)Bb * N2c * Cc;
  float* vn2 = kv2 + (size_t)Bb * N2c * Cc;
  float* fend = vn2 + (size_t)Bb * N2c * (Cc / 2);
  unsigned short* wh = (unsigned short*)fend;        // [4][65536] hi
  unsigned short* wl = wh + (size_t)4 * 65536;       // [4][65536] lo

  // 0) split weights: order = q_w, kv1_w, kv2_w, proj_w
  cvt4<<<dim3(64, 4), 256, 0, stream>>>(q_w, kv1_w, kv2_w, proj_w, wh, wl);
  // 1) q = x @ q_w^T
  gemm_mfma<false><<<512, 256, 0, stream>>>(x, wh, wl, nullptr, q);
  // 2) spatial reductions + LN + GELU
  down_ln_gelu<4, 16><<<dim3(N1c, Bb), 256, 0, stream>>>(x, sr1_w, sr1_b, ln1_g, ln1_b, x1);
  down_ln_gelu<8, 8><<<dim3(N2c, Bb), 256, 0, stream>>>(x, sr2_w, sr2_b, ln2_g, ln2_b, x2);
  // 3) kv projections
  gemm_mfma<false><<<32, 256, 0, stream>>>(x1, wh + 65536,     wl + 65536,     nullptr, kv1);
  gemm_mfma<false><<<8,  256, 0, stream>>>(x2, wh + 2 * 65536, wl + 2 * 65536, nullptr, kv2);
  // 4) v + local depthwise conv
  vconv<16><<<dim3(N1c, Bb), 128, 0, stream>>>(kv1, lc1_w, lc1_b, vn1);
  vconv<8> <<<dim3(N2c, Bb), 128, 0, stream>>>(kv2, lc2_w, lc2_b, vn2);
  // 5) attention (in-place on q)
  attn2<256><<<dim3(16, 4, Bb), 256, 0, stream>>>(q, kv1, vn1, 0);
  attn2<64> <<<dim3(16, 4, Bb), 256, 0, stream>>>(q, kv2, vn2, 1);
  // 6) projection + bias
  gemm_mfma<true><<<512, 256, 0, stream>>>(q, wh + 3 * 65536, wl + 3 * 65536, proj_b, out);
}

// Round 3
// 151.309 us; speedup vs baseline: 2.2718x; 1.6247x over previous
//
#include <hip/hip_runtime.h>
#include <math.h>

// Problem constants (fixed by setup_inputs: B=8, H=W=64, C=256, sr=8)
static constexpr int Bb  = 8;
static constexpr int Nn  = 4096;   // H*W
static constexpr int Cc  = 256;
static constexpr int Wd  = 64;     // image H == W
static constexpr int N1c = 256;    // 16x16 after 4x down
static constexpr int N2c = 64;     // 8x8 after 8x down

typedef __attribute__((ext_vector_type(8)))  short s16x8;   // 8 bf16 (4 VGPR)
typedef __attribute__((ext_vector_type(4)))  float f32x4v;  // MFMA acc

__device__ __forceinline__ unsigned short f2bf(float f) {
  unsigned u = __float_as_uint(f);
  unsigned r = (u + 0x7fffu + ((u >> 16) & 1u)) >> 16;   // RTN-even
  return (unsigned short)r;
}
__device__ __forceinline__ float bf2f(unsigned short h) {
  return __uint_as_float(((unsigned)h) << 16);
}

// ============ prepass: split 4 [256x256] fp32 weights into bf16 hi/lo ============
__global__ __launch_bounds__(256)
void cvt4(const float* __restrict__ w0, const float* __restrict__ w1,
          const float* __restrict__ w2, const float* __restrict__ w3,
          unsigned short* __restrict__ hi, unsigned short* __restrict__ lo) {
  const int wsel = blockIdx.y;
  const float* w = wsel == 0 ? w0 : wsel == 1 ? w1 : wsel == 2 ? w2 : w3;
  const int i = (blockIdx.x * 256 + threadIdx.x) * 4;
  float4 v = *(const float4*)(w + i);
  unsigned short h0 = f2bf(v.x), h1 = f2bf(v.y), h2 = f2bf(v.z), h3 = f2bf(v.w);
  ushort4 hh = make_ushort4(h0, h1, h2, h3);
  ushort4 ll = make_ushort4(f2bf(v.x - bf2f(h0)), f2bf(v.y - bf2f(h1)),
                            f2bf(v.z - bf2f(h2)), f2bf(v.w - bf2f(h3)));
  *(ushort4*)(hi + (size_t)wsel * 65536 + i) = hh;
  *(ushort4*)(lo + (size_t)wsel * 65536 + i) = ll;
}

// ============ GEMM: Out[m,n] = sum_k A[m,k]*W[n,k] (+bias), split-bf16 MFMA =======
template<bool BIAS>
__global__ __launch_bounds__(256)
void gemm_mfma(const float* __restrict__ A, const unsigned short* __restrict__ Wh,
               const unsigned short* __restrict__ Wl, const float* __restrict__ bias,
               float* __restrict__ Out) {
  __shared__ unsigned short Ah[64][40], Al[64][40];
  __shared__ unsigned short BhS[256][40], BlS[256][40];
  const int tid  = threadIdx.x;
  const int lane = tid & 63, wid = tid >> 6;
  const int m0 = blockIdx.x * 64;
  const int ar = tid >> 2;
  const int ak = (tid & 3) * 8;

  f32x4v acc[4][4] = {};

  const float*          Arow  = A  + (size_t)(m0 + ar) * 256 + ak;
  const unsigned short* WhRow = Wh + (size_t)tid * 256;
  const unsigned short* WlRow = Wl + (size_t)tid * 256;

  for (int k0 = 0; k0 < 256; k0 += 32) {
    float4 a0 = *(const float4*)(Arow + k0);
    float4 a1 = *(const float4*)(Arow + k0 + 4);
    uint4 wh0 = *(const uint4*)(WhRow + k0);
    uint4 wh1 = *(const uint4*)(WhRow + k0 + 8);
    uint4 wh2 = *(const uint4*)(WhRow + k0 + 16);
    uint4 wh3 = *(const uint4*)(WhRow + k0 + 24);
    uint4 wl0 = *(const uint4*)(WlRow + k0);
    uint4 wl1 = *(const uint4*)(WlRow + k0 + 8);
    uint4 wl2 = *(const uint4*)(WlRow + k0 + 16);
    uint4 wl3 = *(const uint4*)(WlRow + k0 + 24);
    __syncthreads();
    float fv[8] = {a0.x, a0.y, a0.z, a0.w, a1.x, a1.y, a1.z, a1.w};
    unsigned h[8], l[8];
#pragma unroll
    for (int i = 0; i < 8; ++i) {
      h[i] = f2bf(fv[i]);
      l[i] = f2bf(fv[i] - bf2f((unsigned short)h[i]));
    }
    uint4 hp = make_uint4(h[0] | (h[1] << 16), h[2] | (h[3] << 16),
                          h[4] | (h[5] << 16), h[6] | (h[7] << 16));
    uint4 lp = make_uint4(l[0] | (l[1] << 16), l[2] | (l[3] << 16),
                          l[4] | (l[5] << 16), l[6] | (l[7] << 16));
    *(uint4*)&Ah[ar][ak] = hp;
    *(uint4*)&Al[ar][ak] = lp;
    *(uint4*)&BhS[tid][0]  = wh0; *(uint4*)&BhS[tid][8]  = wh1;
    *(uint4*)&BhS[tid][16] = wh2; *(uint4*)&BhS[tid][24] = wh3;
    *(uint4*)&BlS[tid][0]  = wl0; *(uint4*)&BlS[tid][8]  = wl1;
    *(uint4*)&BlS[tid][16] = wl2; *(uint4*)&BlS[tid][24] = wl3;
    __syncthreads();
    const int koff = (lane >> 4) * 8;
    const int arow = lane & 15;
    s16x8 ah[4], al4[4];
#pragma unroll
    for (int mt = 0; mt < 4; ++mt) {
      ah[mt]  = *(const s16x8*)&Ah[mt * 16 + arow][koff];
      al4[mt] = *(const s16x8*)&Al[mt * 16 + arow][koff];
    }
#pragma unroll
    for (int nt = 0; nt < 4; ++nt) {
      const int col = wid * 64 + nt * 16 + (lane & 15);
      s16x8 bh = *(const s16x8*)&BhS[col][koff];
      s16x8 bl = *(const s16x8*)&BlS[col][koff];
#pragma unroll
      for (int mt = 0; mt < 4; ++mt) {
        acc[mt][nt] = __builtin_amdgcn_mfma_f32_16x16x32_bf16(ah[mt],  bh, acc[mt][nt], 0, 0, 0);
        acc[mt][nt] = __builtin_amdgcn_mfma_f32_16x16x32_bf16(ah[mt],  bl, acc[mt][nt], 0, 0, 0);
        acc[mt][nt] = __builtin_amdgcn_mfma_f32_16x16x32_bf16(al4[mt], bh, acc[mt][nt], 0, 0, 0);
      }
    }
  }
#pragma unroll
  for (int nt = 0; nt < 4; ++nt) {
    const int col = wid * 64 + nt * 16 + (lane & 15);
    const float bv = BIAS ? bias[col] : 0.f;
#pragma unroll
    for (int mt = 0; mt < 4; ++mt) {
#pragma unroll
      for (int r = 0; r < 4; ++r) {
        const int row = m0 + mt * 16 + (lane >> 4) * 4 + r;
        Out[(size_t)row * 256 + col] = acc[mt][nt][r] + bv;
      }
    }
  }
}

// =============== fused: depthwise KSxKS stride-KS conv + bias + LN + exact GELU =======
template<int KS, int HO>
__global__ __launch_bounds__(256)
void down_ln_gelu(const float* __restrict__ x, const float* __restrict__ w,
                  const float* __restrict__ cb, const float* __restrict__ g,
                  const float* __restrict__ lb, float* __restrict__ xo) {
  const int b = blockIdx.y;
  const int n1 = blockIdx.x;
  const int i = n1 / HO, j = n1 % HO;
  const int c = threadIdx.x;
  const float* wc = w + c * KS * KS;
  const float* xb = x + ((size_t)b * Nn) * Cc + c;
  float acc = cb[c];
#pragma unroll
  for (int dy = 0; dy < KS; ++dy) {
#pragma unroll
    for (int dx = 0; dx < KS; ++dx) {
      int n = (i * KS + dy) * Wd + (j * KS + dx);
      acc = fmaf(wc[dy * KS + dx], xb[(size_t)n * Cc], acc);
    }
  }
  float s = acc, s2 = acc * acc;
#pragma unroll
  for (int off = 32; off; off >>= 1) {
    s  += __shfl_down(s, off);
    s2 += __shfl_down(s2, off);
  }
  __shared__ float rs[4], rq[4];
  if ((c & 63) == 0) { rs[c >> 6] = s; rq[c >> 6] = s2; }
  __syncthreads();
  float sum = rs[0] + rs[1] + rs[2] + rs[3];
  float sq  = rq[0] + rq[1] + rq[2] + rq[3];
  float mean = sum * (1.f / Cc);
  float var  = sq * (1.f / Cc) - mean * mean;
  float xn = (acc - mean) * rsqrtf(var + 1e-5f) * g[c] + lb[c];
  float gel = 0.5f * xn * (1.f + erff(xn * 0.70710678118654752440f));
  xo[((size_t)b * (HO * HO) + n1) * Cc + c] = gel;
}

// =============== v_new = v + dwconv3x3(v) + bias  (v = channels 128.. of kv) =========
template<int HS>
__global__ __launch_bounds__(128)
void vconv(const float* __restrict__ kv, const float* __restrict__ w,
           const float* __restrict__ bias, float* __restrict__ vo) {
  constexpr int NS = HS * HS;
  const int b = blockIdx.y;
  const int n1 = blockIdx.x;
  const int i = n1 / HS, j = n1 % HS;
  const int c = threadIdx.x;
  const float* vb = kv + ((size_t)b * NS) * Cc + 128 + c;
  const float* wc = w + c * 9;
  float acc = bias[c];
#pragma unroll
  for (int dy = 0; dy < 3; ++dy) {
    int ii = i + dy - 1;
    if (ii < 0 || ii >= HS) continue;
#pragma unroll
    for (int dx = 0; dx < 3; ++dx) {
      int jj = j + dx - 1;
      if (jj < 0 || jj >= HS) continue;
      acc = fmaf(wc[dy * 3 + dx], vb[(size_t)(ii * HS + jj) * Cc], acc);
    }
  }
  vo[((size_t)b * NS + n1) * 128 + c] = acc + vb[(size_t)n1 * Cc];
}

// =============== attention v3: MFMA, swapped QK^T, exact softmax =====================
// Block = 4 waves, 256 queries; grid (16 qchunk, 4 h, 8 b). In-place q -> o.
// Per wave, per 16-q tile: S^T = mfma(Kfrag, Qfrag) x NT; softmax in-reg
// (reduce over lanes {q,q+16,q+32,q+48}); P^T -> bf16 via per-wave LDS; PV with
// V^T A-frags held in registers. V fp32 staging buffer is reused as P buffer.
template<int NS>
__global__ __launch_bounds__(256, 2)
void attn_mfma(float* __restrict__ qo, const float* __restrict__ kv,
               const float* __restrict__ vnew, const int branch) {
  constexpr int NT = NS / 16, NC = NS / 32, PS = NS + 8;
  constexpr float KC = 0.17677669529663688f * 1.4426950408889634f; // scale*log2e
  __shared__ unsigned short Klds[NS][40];
  constexpr int VB = NS * 36 * 4, PB = 4 * 16 * PS * 2;
  constexpr int USZ = (VB > PB) ? VB : PB;
  __shared__ __align__(16) char Ubuf[USZ];
  float (*vs)[36] = (float (*)[36])Ubuf;

  const int tid = threadIdx.x, lane = tid & 63, wid = tid >> 6;
  const int g = lane >> 4, qi = lane & 15;
  const int h = blockIdx.y, b = blockIdx.z;
  const int ck = h * 32;
  const int cq = branch * 128 + h * 32;

  // ---- stage K (bf16, [key][40]) and V (fp32, [key][36]) ----
  for (int r = tid; r < NS; r += 256) {
    const float* kp = kv   + ((size_t)(b * NS + r)) * 256 + ck;
    const float* vp = vnew + ((size_t)(b * NS + r)) * 128 + ck;
    float kf[32];
#pragma unroll
    for (int i = 0; i < 8; ++i) *(float4*)&kf[i * 4] = *(const float4*)(kp + i * 4);
    unsigned kw[16];
#pragma unroll
    for (int i = 0; i < 16; ++i)
      kw[i] = f2bf(kf[2 * i]) | ((unsigned)f2bf(kf[2 * i + 1]) << 16);
#pragma unroll
    for (int i = 0; i < 4; ++i)
      *(uint4*)&Klds[r][i * 8] = make_uint4(kw[i*4], kw[i*4+1], kw[i*4+2], kw[i*4+3]);
#pragma unroll
    for (int i = 0; i < 8; ++i) *(float4*)&vs[r][i * 4] = *(const float4*)(vp + i * 4);
  }
  __syncthreads();

  // ---- build V^T A-frags in registers: vt[dt][c] elem j = V[32c+8g+j][16dt+qi] ----
  s16x8 vt[2][NC];
#pragma unroll
  for (int dt = 0; dt < 2; ++dt)
#pragma unroll
    for (int c = 0; c < NC; ++c)
#pragma unroll
      for (int j = 0; j < 8; ++j)
        vt[dt][c][j] = (short)f2bf(vs[32 * c + 8 * g + j][16 * dt + qi]);
  __syncthreads();   // V region reused as P below

  unsigned short* Pw = (unsigned short*)Ubuf + (size_t)(wid * 16 + qi) * PS;

  for (int qt = 0; qt < 4; ++qt) {
    const int qrow = blockIdx.x * 256 + wid * 64 + qt * 16 + qi;
    float* qp = qo + ((size_t)b * Nn + qrow) * 256 + cq;
    // Q B-frag: elem j = Q[qi][8g+j]
    float qf0[4], qf1[4];
    *(float4*)qf0 = *(const float4*)(qp + 8 * g);
    *(float4*)qf1 = *(const float4*)(qp + 8 * g + 4);
    s16x8 qfrag;
#pragma unroll
    for (int j = 0; j < 4; ++j) qfrag[j] = (short)f2bf(qf0[j]);
#pragma unroll
    for (int j = 0; j < 4; ++j) qfrag[4 + j] = (short)f2bf(qf1[j]);
    // ---- S^T tiles: s[t][r] = S[key=16t+4g+r][q=qi] ----
    f32x4v s[NT];
#pragma unroll
    for (int t = 0; t < NT; ++t) {
      s16x8 kf = *(const s16x8*)&Klds[16 * t + qi][8 * g];
      s[t] = __builtin_amdgcn_mfma_f32_16x16x32_bf16(kf, qfrag,
                                                     (f32x4v){0.f, 0.f, 0.f, 0.f}, 0, 0, 0);
    }
    // ---- softmax (exact; cross-lane over {qi, qi+16, qi+32, qi+48}) ----
    float m = s[0][0];
#pragma unroll
    for (int t = 0; t < NT; ++t)
      m = fmaxf(m, fmaxf(fmaxf(s[t][0], s[t][1]), fmaxf(s[t][2], s[t][3])));
    m = fmaxf(m, __shfl_xor(m, 16));
    m = fmaxf(m, __shfl_xor(m, 32));
    float l = 0.f;
#pragma unroll
    for (int t = 0; t < NT; ++t)
#pragma unroll
      for (int r = 0; r < 4; ++r) {
        float p = exp2f((s[t][r] - m) * KC);
        s[t][r] = p; l += p;
      }
    l += __shfl_xor(l, 16);
    l += __shfl_xor(l, 32);
    // ---- pack P^T -> bf16, write to per-wave LDS rows [q][key] ----
#pragma unroll
    for (int t = 0; t < NT; ++t) {
      unsigned w0 = f2bf(s[t][0]) | ((unsigned)f2bf(s[t][1]) << 16);
      unsigned w1 = f2bf(s[t][2]) | ((unsigned)f2bf(s[t][3]) << 16);
      *(uint2*)&Pw[16 * t + 4 * g] = make_uint2(w0, w1);
    }
    // ---- PV: O^T[d,q] accumulate over key chunks ----
    f32x4v o0 = {0.f, 0.f, 0.f, 0.f}, o1 = {0.f, 0.f, 0.f, 0.f};
#pragma unroll
    for (int c = 0; c < NC; ++c) {
      s16x8 pf = *(const s16x8*)&Pw[32 * c + 8 * g];
      o0 = __builtin_amdgcn_mfma_f32_16x16x32_bf16(vt[0][c], pf, o0, 0, 0, 0);
      o1 = __builtin_amdgcn_mfma_f32_16x16x32_bf16(vt[1][c], pf, o1, 0, 0, 0);
    }
    const float inv = 1.f / l;
    float4 O0 = make_float4(o0[0] * inv, o0[1] * inv, o0[2] * inv, o0[3] * inv);
    float4 O1 = make_float4(o1[0] * inv, o1[1] * inv, o1[2] * inv, o1[3] * inv);
    *(float4*)(qp + 4 * g)      = O0;   // d = 4g..4g+3
    *(float4*)(qp + 16 + 4 * g) = O1;   // d = 16+4g..16+4g+3
  }
}

extern "C" void kernel_launch(void* const* d_in, const int* in_sizes, int n_in,
                              void* d_out, int out_size, void* d_ws, size_t ws_size,
                              hipStream_t stream) {
  const float* x      = (const float*)d_in[0];
  const float* q_w    = (const float*)d_in[1];
  const float* kv1_w  = (const float*)d_in[2];
  const float* kv2_w  = (const float*)d_in[3];
  const float* proj_w = (const float*)d_in[4];
  const float* proj_b = (const float*)d_in[5];
  const float* sr1_w  = (const float*)d_in[6];
  const float* sr1_b  = (const float*)d_in[7];
  const float* sr2_w  = (const float*)d_in[8];
  const float* sr2_b  = (const float*)d_in[9];
  const float* ln1_g  = (const float*)d_in[10];
  const float* ln1_b  = (const float*)d_in[11];
  const float* ln2_g  = (const float*)d_in[12];
  const float* ln2_b  = (const float*)d_in[13];
  const float* lc1_w  = (const float*)d_in[14];
  const float* lc1_b  = (const float*)d_in[15];
  const float* lc2_w  = (const float*)d_in[16];
  const float* lc2_b  = (const float*)d_in[17];
  float* out = (float*)d_out;
  float* ws  = (float*)d_ws;

  float* q   = ws;                                   // [B,N,C] (becomes o in-place)
  float* x1  = q   + (size_t)Bb * Nn  * Cc;
  float* kv1 = x1  + (size_t)Bb * N1c * Cc;
  float* vn1 = kv1 + (size_t)Bb * N1c * Cc;
  float* x2  = vn1 + (size_t)Bb * N1c * (Cc / 2);
  float* kv2 = x2  + (size_t)Bb * N2c * Cc;
  float* vn2 = kv2 + (size_t)Bb * N2c * Cc;
  float* fend = vn2 + (size_t)Bb * N2c * (Cc / 2);
  unsigned short* wh = (unsigned short*)fend;        // [4][65536] hi
  unsigned short* wl = wh + (size_t)4 * 65536;       // [4][65536] lo

  cvt4<<<dim3(64, 4), 256, 0, stream>>>(q_w, kv1_w, kv2_w, proj_w, wh, wl);
  gemm_mfma<false><<<512, 256, 0, stream>>>(x, wh, wl, nullptr, q);
  down_ln_gelu<4, 16><<<dim3(N1c, Bb), 256, 0, stream>>>(x, sr1_w, sr1_b, ln1_g, ln1_b, x1);
  down_ln_gelu<8, 8><<<dim3(N2c, Bb), 256, 0, stream>>>(x, sr2_w, sr2_b, ln2_g, ln2_b, x2);
  gemm_mfma<false><<<32, 256, 0, stream>>>(x1, wh + 65536,     wl + 65536,     nullptr, kv1);
  gemm_mfma<false><<<8,  256, 0, stream>>>(x2, wh + 2 * 65536, wl + 2 * 65536, nullptr, kv2);
  vconv<16><<<dim3(N1c, Bb), 128, 0, stream>>>(kv1, lc1_w, lc1_b, vn1);
  vconv<8> <<<dim3(N2c, Bb), 128, 0, stream>>>(kv2, lc2_w, lc2_b, vn2);
  attn_mfma<256><<<dim3(16, 4, Bb), 256, 0, stream>>>(q, kv1, vn1, 0);
  attn_mfma<64> <<<dim3(16, 4, Bb), 256, 0, stream>>>(q, kv2, vn2, 1);
  gemm_mfma<true><<<512, 256, 0, stream>>>(q, wh + 3 * 65536, wl + 3 * 65536, proj_b, out);
}